// Round 11
// baseline (103.726 us; speedup 1.0000x reference)
//
#include <hip/hip_runtime.h>
#include <cstdint>
#include <cstddef>

#define NSEQ 1024
#define BATCH 8
#define CMODEL 512
#define NHEAD 8
#define HDIM 64
#define CAP 64
#define FLTMAX 3.402823466e+38f

typedef short bf16x8 __attribute__((ext_vector_type(8)));
typedef float f32x4 __attribute__((ext_vector_type(4)));
typedef unsigned short ushort8v __attribute__((ext_vector_type(8)));
typedef unsigned short ushort2v __attribute__((ext_vector_type(2)));

__device__ inline unsigned short f2bf(float f) {
    unsigned int u = __builtin_bit_cast(unsigned int, f);
    u += 0x7fffu + ((u >> 16) & 1u);
    return (unsigned short)(u >> 16);
}
__device__ inline float bf2f(unsigned short u) {
    return __builtin_bit_cast(float, (unsigned int)u << 16);
}

#define GLDS16(gsrc, ldst) \
    __builtin_amdgcn_global_load_lds((const __attribute__((address_space(1))) void*)(gsrc), \
                                     (__attribute__((address_space(3))) void*)(ldst), 16, 0, 0)

// ---------------------------------------------------------------------------
// prepA: blocks 0..511 weight fp32->bf16; 512..543 zero row_cnt;
// 544..607 column-sum of value (vm_raw); 608..623 SoA transpose of positions.
// ---------------------------------------------------------------------------
__global__ __launch_bounds__(256) void prepA(const float* __restrict__ w0,
                                             const float* __restrict__ w1,
                                             const float* __restrict__ w2,
                                             const float* __restrict__ w3,
                                             const float* __restrict__ value,
                                             const float* __restrict__ tgtp,
                                             const float* __restrict__ srcp,
                                             unsigned short* __restrict__ o0,
                                             unsigned short* __restrict__ o1,
                                             unsigned short* __restrict__ o2,
                                             unsigned short* __restrict__ o3,
                                             unsigned int* __restrict__ zp,
                                             float* __restrict__ vm_raw,
                                             float* __restrict__ tgt_soa,
                                             float* __restrict__ src_soa) {
    const int bid = blockIdx.x;
    const int tid = threadIdx.x;
    if (bid < 512) {
        const int idx = bid * 256 + tid;
        const int seg = idx >> 15;
        const int c   = idx & 32767;
        const float* src = seg == 0 ? w0 : seg == 1 ? w1 : seg == 2 ? w2 : w3;
        unsigned short* dst = seg == 0 ? o0 : seg == 1 ? o1 : seg == 2 ? o2 : o3;
        const float4 v0 = *(const float4*)(src + (size_t)c * 8);
        const float4 v1 = *(const float4*)(src + (size_t)c * 8 + 4);
        ushort8v u;
        u[0] = f2bf(v0.x); u[1] = f2bf(v0.y); u[2] = f2bf(v0.z); u[3] = f2bf(v0.w);
        u[4] = f2bf(v1.x); u[5] = f2bf(v1.y); u[6] = f2bf(v1.z); u[7] = f2bf(v1.w);
        *(ushort8v*)(dst + (size_t)c * 8) = u;
        return;
    }
    if (bid < 544) {
        zp[(bid - 512) * 256 + tid] = 0u;
        return;
    }
    if (bid < 608) {
        const int cb = bid - 544;
        const int b = cb >> 3, cg = cb & 7;
        const int ts = tid >> 6, c = cg * 64 + (tid & 63);
        float s = 0.f;
        for (int i = 0; i < 256; ++i) {
            const int t = ts * 256 + i;
            s += value[((size_t)t * BATCH + b) * CMODEL + c];
        }
        __shared__ float sh[4][64];
        sh[ts][tid & 63] = s;
        __syncthreads();
        if (ts == 0)
            vm_raw[b * CMODEL + c] = sh[0][tid & 63] + sh[1][tid & 63] +
                                     sh[2][tid & 63] + sh[3][tid & 63];
        return;
    }
    const int tb = bid - 608;
    const int which = tb >> 3, b = tb & 7;
    const float* src = which == 0 ? tgtp : srcp;
    float* dst = which == 0 ? tgt_soa : src_soa;
    for (int t = tid; t < NSEQ; t += 256) {
        const float* p = src + ((size_t)t * BATCH + b) * 3;
        dst[(b * 3 + 0) * NSEQ + t] = p[0];
        dst[(b * 3 + 1) * NSEQ + t] = p[1];
        dst[(b * 3 + 2) * NSEQ + t] = p[2];
    }
}

// ---------------------------------------------------------------------------
// megaB: complementary fusion.
// blocks 0..7     : vm GEMV (VALU)
// blocks 8..2055  : wave-parallel top-5 (DS-shuffle / latency bound)
// blocks 2056..8199: q/k/v fp32->bf16 convert (pure HBM streaming)
// ---------------------------------------------------------------------------
__global__ __launch_bounds__(256) void megaB(const float* __restrict__ a0,
                                             const float* __restrict__ a1,
                                             const float* __restrict__ a2,
                                             unsigned short* __restrict__ oa0,
                                             unsigned short* __restrict__ oa1,
                                             unsigned short* __restrict__ oa2,
                                             const float* __restrict__ src_soa,
                                             const float* __restrict__ tgt_soa,
                                             int* __restrict__ row_cnt,
                                             int* __restrict__ row_list,
                                             const unsigned short* __restrict__ Wv,
                                             const float* __restrict__ bv,
                                             const float* __restrict__ vm_raw,
                                             float* __restrict__ vm) {
    const int p = blockIdx.x;
    const int tid = threadIdx.x;

    if (p < 8) {
        const int bsel = p;
        const int c0 = tid * 2;
        float s0 = 0.f, s1 = 0.f;
        const unsigned short* w0r = Wv + (size_t)c0 * CMODEL;
        const unsigned short* w1r = w0r + CMODEL;
        const float* vr = vm_raw + bsel * CMODEL;
        for (int k8 = 0; k8 < 64; ++k8) {
            const ushort8v w0 = *(const ushort8v*)(w0r + k8 * 8);
            const ushort8v w1 = *(const ushort8v*)(w1r + k8 * 8);
            const float4 va = *(const float4*)(vr + k8 * 8);
            const float4 vb = *(const float4*)(vr + k8 * 8 + 4);
            s0 += va.x * bf2f(w0[0]) + va.y * bf2f(w0[1]) + va.z * bf2f(w0[2]) + va.w * bf2f(w0[3])
                + vb.x * bf2f(w0[4]) + vb.y * bf2f(w0[5]) + vb.z * bf2f(w0[6]) + vb.w * bf2f(w0[7]);
            s1 += va.x * bf2f(w1[0]) + va.y * bf2f(w1[1]) + va.z * bf2f(w1[2]) + va.w * bf2f(w1[3])
                + vb.x * bf2f(w1[4]) + vb.y * bf2f(w1[5]) + vb.z * bf2f(w1[6]) + vb.w * bf2f(w1[7]);
        }
        vm[bsel * CMODEL + c0]     = s0 * (1.f / (float)NSEQ) + bv[c0];
        vm[bsel * CMODEL + c0 + 1] = s1 * (1.f / (float)NSEQ) + bv[c0 + 1];
        return;
    }

    if (p >= 2056) {
        const unsigned int idx = (unsigned int)(p - 2056) * 256u + tid;   // < 1572864
        const unsigned int seg = idx >> 19;
        const unsigned int c   = idx & 524287u;
        const float* src = seg == 0 ? a0 : seg == 1 ? a1 : a2;
        unsigned short* dst = seg == 0 ? oa0 : seg == 1 ? oa1 : oa2;
        const float4 v0 = *(const float4*)(src + (size_t)c * 8);
        const float4 v1 = *(const float4*)(src + (size_t)c * 8 + 4);
        ushort8v u;
        u[0] = f2bf(v0.x); u[1] = f2bf(v0.y); u[2] = f2bf(v0.z); u[3] = f2bf(v0.w);
        u[4] = f2bf(v1.x); u[5] = f2bf(v1.y); u[6] = f2bf(v1.z); u[7] = f2bf(v1.w);
        *(ushort8v*)(dst + (size_t)c * 8) = u;
        return;
    }

    // top-5 blocks
    const int w = tid >> 6, lane = tid & 63;
    const int wg = (p - 8) * 4 + w;             // 0..8191
    const int s = wg & 1023, b = wg >> 10;

    const float* tx = tgt_soa + (b * 3 + 0) * NSEQ;
    const float* ty = tgt_soa + (b * 3 + 1) * NSEQ;
    const float* tz = tgt_soa + (b * 3 + 2) * NSEQ;
    const float sx = src_soa[(b * 3 + 0) * NSEQ + s];
    const float sy = src_soa[(b * 3 + 1) * NSEQ + s];
    const float sz = src_soa[(b * 3 + 2) * NSEQ + s];

    float dv[16];
    #pragma unroll
    for (int i = 0; i < 16; ++i) {
        const int t = i * 64 + lane;
        const float dx = tx[t] - sx;
        const float dy = ty[t] - sy;
        const float dz = tz[t] - sz;
        dv[i] = dx * dx + dy * dy + dz * dz;
    }

    #pragma unroll
    for (int k = 0; k < 5; ++k) {
        float bvv = FLTMAX;
        int   bii = 0x7fffffff;
        #pragma unroll
        for (int i = 0; i < 16; ++i) {
            if (dv[i] < bvv) { bvv = dv[i]; bii = i * 64 + lane; }
        }
        #pragma unroll
        for (int off = 1; off < 64; off <<= 1) {
            const float ov = __shfl_xor(bvv, off);
            const int   oi = __shfl_xor(bii, off);
            if (ov < bvv || (ov == bvv && oi < bii)) { bvv = ov; bii = oi; }
        }
        if (lane == (bii & 63)) {
            #pragma unroll
            for (int i = 0; i < 16; ++i)
                if (bii == i * 64 + lane) dv[i] = FLTMAX;
        }
        if (lane == 0) {
            const int pos = atomicAdd(&row_cnt[b * NSEQ + bii], 1);
            if (pos < CAP) row_list[((size_t)b * NSEQ + bii) * CAP + pos] = s;
        }
    }
}

// ---------------------------------------------------------------------------
// gemm_proj: R6's all-GLDS ring-3 counted-vmcnt body (bf16 A, proven) +
// bijective XCD swizzle over a 1D grid of 768.
// Tile 128x128, BK=32, 4 waves 2x2, wave 64x64 (4x4 frags).
// Per iter: vmcnt(4) [tile t+1 stays in flight]; barrier; STAGE(t+2); COMPUTE(t).
// Writes bf16 (b,t,c).
// ---------------------------------------------------------------------------
__global__ __launch_bounds__(256, 3) void gemm_proj(const unsigned short* __restrict__ Aq,
                                                    const unsigned short* __restrict__ Ak,
                                                    const unsigned short* __restrict__ Av,
                                                    const unsigned short* __restrict__ Wq,
                                                    const unsigned short* __restrict__ Wk,
                                                    const unsigned short* __restrict__ Wv,
                                                    const float* __restrict__ bq,
                                                    const float* __restrict__ bk,
                                                    const float* __restrict__ bv,
                                                    unsigned short* __restrict__ oq,
                                                    unsigned short* __restrict__ ok,
                                                    unsigned short* __restrict__ ov) {
    __shared__ __align__(16) unsigned short smem[3 * 8192];
    const int p = blockIdx.x;                       // 0..767
    const int logical = (p & 7) * 96 + (p >> 3);
    const int z = logical >> 8;
    const int r = logical & 255;
    const int m0 = (r >> 2) * 128, n0 = (r & 3) * 128;
    const unsigned short* Abf = z == 0 ? Aq : z == 1 ? Ak : Av;
    const unsigned short* Wbf = z == 0 ? Wq : z == 1 ? Wk : Wv;
    const float* bias = z == 0 ? bq : z == 1 ? bk : bv;
    unsigned short* outp = z == 0 ? oq : z == 1 ? ok : ov;
    const float scale = z == 0 ? 0.125f : 1.0f;

    const int tid = threadIdx.x;
    const int l = tid & 63, w = tid >> 6;
    const int wr = (w >> 1) * 64, wc = (w & 1) * 64;
    const int lr = l & 15, g = l >> 4;

    f32x4 acc[4][4] = {};

    const int rowX = tid >> 2;
    const int kg0  = (tid & 3) ^ ((rowX >> 1) & 3);
    const unsigned short* aS0 = Abf + (size_t)(m0 + rowX) * CMODEL + kg0 * 8;
    const unsigned short* aS1 = aS0 + (size_t)64 * CMODEL;
    const unsigned short* bS0 = Wbf + (size_t)(n0 + rowX) * CMODEL + kg0 * 8;
    const unsigned short* bS1 = bS0 + (size_t)64 * CMODEL;
    const int wb = w * 512;

    auto STAGE = [&](int k0, int buf) {
        unsigned short* bb = smem + buf * 8192;
        GLDS16(aS0 + k0, bb + wb);
        GLDS16(aS1 + k0, bb + 2048 + wb);
        GLDS16(bS0 + k0, bb + 4096 + wb);
        GLDS16(bS1 + k0, bb + 6144 + wb);
    };
    auto COMPUTE = [&](const unsigned short* base) {
        bf16x8 af[4], bg[4];
        #pragma unroll
        for (int i = 0; i < 4; ++i) {
            const int ra = wr + i * 16 + lr;
            af[i] = *(const bf16x8*)(base + ra * 32 + ((g ^ ((ra >> 1) & 3)) << 3));
        }
        #pragma unroll
        for (int j = 0; j < 4; ++j) {
            const int rb = wc + j * 16 + lr;
            bg[j] = *(const bf16x8*)(base + 4096 + rb * 32 + ((g ^ ((rb >> 1) & 3)) << 3));
        }
        #pragma unroll
        for (int i = 0; i < 4; ++i)
            #pragma unroll
            for (int j = 0; j < 4; ++j)
                acc[i][j] = __builtin_amdgcn_mfma_f32_16x16x32_bf16(af[i], bg[j], acc[i][j], 0, 0, 0);
    };

    STAGE(0, 0);
    STAGE(32, 1);

    int cur = 0;
    for (int t = 0; t < 15; ++t) {
        asm volatile("s_waitcnt vmcnt(4)" ::: "memory");
        __builtin_amdgcn_s_barrier();
        if (t < 14) {
            int nb = cur + 2; if (nb >= 3) nb -= 3;
            STAGE((t + 2) * 32, nb);
        }
        COMPUTE(smem + cur * 8192);
        ++cur; if (cur == 3) cur = 0;
    }
    asm volatile("s_waitcnt vmcnt(0)" ::: "memory");
    __builtin_amdgcn_s_barrier();
    COMPUTE(smem + cur * 8192);

    #pragma unroll
    for (int i = 0; i < 4; ++i) {
        #pragma unroll
        for (int j = 0; j < 4; ++j) {
            const int col = n0 + wc + j * 16 + lr;
            const float bcol = bias[col];
            #pragma unroll
            for (int rr = 0; rr < 4; ++rr) {
                const int row = m0 + wr + i * 16 + g * 4 + rr;
                const float val = (acc[i][j][rr] + bcol) * scale;
                const int t = row >> 3, bb = row & 7;
                outp[((size_t)(bb * NSEQ + t)) * CMODEL + col] = f2bf(val);
            }
        }
    }
}

// ---------------------------------------------------------------------------
// gemm_out: all-GLDS ring-3, tile 128x64, 512 blocks (2/CU), vmcnt(3).
// ---------------------------------------------------------------------------
__global__ __launch_bounds__(256, 3) void gemm_out(const unsigned short* __restrict__ Abf,
                                                   const unsigned short* __restrict__ Wbf,
                                                   const float* __restrict__ bias,
                                                   float* __restrict__ out) {
    __shared__ __align__(16) unsigned short smem[3 * 6144];
    const int p = blockIdx.x;                       // 0..511
    const int logical = (p & 7) * 64 + (p >> 3);
    const int m0 = (logical >> 3) * 128, n0 = (logical & 7) * 64;

    const int tid = threadIdx.x;
    const int l = tid & 63, w = tid >> 6;
    const int wr = (w >> 1) * 64, wc = (w & 1) * 32;
    const int lr = l & 15, g = l >> 4;

    f32x4 acc[4][2] = {};

    const int rowX = tid >> 2;
    const int kg0  = (tid & 3) ^ ((rowX >> 1) & 3);
    const unsigned short* aS0 = Abf + (size_t)(m0 + rowX) * CMODEL + kg0 * 8;
    const unsigned short* aS1 = aS0 + (size_t)64 * CMODEL;
    const unsigned short* bS0 = Wbf + (size_t)(n0 + rowX) * CMODEL + kg0 * 8;
    const int wb = w * 512;

    auto STAGE = [&](int k0, int buf) {
        unsigned short* bb = smem + buf * 6144;
        GLDS16(aS0 + k0, bb + wb);
        GLDS16(aS1 + k0, bb + 2048 + wb);
        GLDS16(bS0 + k0, bb + 4096 + wb);
    };
    auto COMPUTE = [&](const unsigned short* base) {
        bf16x8 af[4], bg[2];
        #pragma unroll
        for (int i = 0; i < 4; ++i) {
            const int ra = wr + i * 16 + lr;
            af[i] = *(const bf16x8*)(base + ra * 32 + ((g ^ ((ra >> 1) & 3)) << 3));
        }
        #pragma unroll
        for (int j = 0; j < 2; ++j) {
            const int rb = wc + j * 16 + lr;
            bg[j] = *(const bf16x8*)(base + 4096 + rb * 32 + ((g ^ ((rb >> 1) & 3)) << 3));
        }
        #pragma unroll
        for (int i = 0; i < 4; ++i)
            #pragma unroll
            for (int j = 0; j < 2; ++j)
                acc[i][j] = __builtin_amdgcn_mfma_f32_16x16x32_bf16(af[i], bg[j], acc[i][j], 0, 0, 0);
    };

    STAGE(0, 0);
    STAGE(32, 1);

    int cur = 0;
    for (int t = 0; t < 15; ++t) {
        asm volatile("s_waitcnt vmcnt(3)" ::: "memory");
        __builtin_amdgcn_s_barrier();
        if (t < 14) {
            int nb = cur + 2; if (nb >= 3) nb -= 3;
            STAGE((t + 2) * 32, nb);
        }
        COMPUTE(smem + cur * 6144);
        ++cur; if (cur == 3) cur = 0;
    }
    asm volatile("s_waitcnt vmcnt(0)" ::: "memory");
    __builtin_amdgcn_s_barrier();
    COMPUTE(smem + cur * 6144);

    #pragma unroll
    for (int i = 0; i < 4; ++i) {
        #pragma unroll
        for (int j = 0; j < 2; ++j) {
            const int col = n0 + wc + j * 16 + lr;
            const float bcol = bias[col];
            #pragma unroll
            for (int r = 0; r < 4; ++r) {
                const int row = m0 + wr + i * 16 + g * 4 + r;
                out[(size_t)row * CMODEL + col] = acc[i][j][r] + bcol;
            }
        }
    }
}

// ---------------------------------------------------------------------------
// sparse_attn: unchanged. One block per (t, b). bf16 q/k/v.
// ---------------------------------------------------------------------------
__global__ __launch_bounds__(256) void sparse_attn(const unsigned short* __restrict__ q_ws,
                                                   const unsigned short* __restrict__ k_ws,
                                                   const unsigned short* __restrict__ v_ws,
                                                   const int* __restrict__ row_cnt,
                                                   const int* __restrict__ row_list,
                                                   const float* __restrict__ vm,
                                                   unsigned short* __restrict__ ctx,
                                                   float* __restrict__ attn_out) {
    const int t = blockIdx.x;
    const int b = blockIdx.y;
    const int tid = threadIdx.x;

    int cnt = row_cnt[b * NSEQ + t];
    if (cnt > CAP) cnt = CAP;

    float* arow = attn_out + ((size_t)b * NSEQ + t) * NSEQ;

    if (cnt == 0) {
        const float u = 1.f / (float)NSEQ;
        const float4 uv = {u, u, u, u};
        ((float4*)arow)[tid] = uv;
        for (int c = tid; c < CMODEL; c += 256)
            ctx[((size_t)t * BATCH + b) * CMODEL + c] = f2bf(vm[b * CMODEL + c]);
        return;
    }

    {
        const float4 zv = {0.f, 0.f, 0.f, 0.f};
        ((float4*)arow)[tid] = zv;
    }

    __shared__ float qs[CMODEL];
    __shared__ float esc[CAP][8];
    __shared__ float denom[8];
    __shared__ int   slist[CAP];

    if (tid < 8) denom[tid] = 0.f;
    if (tid < cnt) slist[tid] = row_list[((size_t)b * NSEQ + t) * CAP + tid];
    {
        const ushort2v qv = *(const ushort2v*)(q_ws + ((size_t)b * NSEQ + t) * CMODEL + tid * 2);
        qs[tid * 2] = bf2f(qv[0]); qs[tid * 2 + 1] = bf2f(qv[1]);
    }
    __syncthreads();

    const int wid = tid >> 6, lane = tid & 63;
    for (int i = wid; i < cnt; i += 4) {
        const int s = slist[i];
        const ushort8v kv = *(const ushort8v*)(k_ws + ((size_t)b * NSEQ + s) * CMODEL + lane * 8);
        const float* qrow = qs + lane * 8;
        float part = 0.f;
        #pragma unroll
        for (int j = 0; j < 8; ++j) part += qrow[j] * bf2f(kv[j]);
        part += __shfl_xor(part, 1);
        part += __shfl_xor(part, 2);
        part += __shfl_xor(part, 4);
        if ((lane & 7) == 0) {
            const int h = lane >> 3;
            const float e = __expf(part);
            esc[i][h] = e;
            atomicAdd(&denom[h], e);
        }
    }
    __syncthreads();

    for (int x = tid; x < cnt * 8; x += 256)
        esc[x >> 3][x & 7] /= denom[x & 7];
    __syncthreads();

    for (int i = tid; i < cnt; i += 256) {
        float pm = 0.f;
        #pragma unroll
        for (int h = 0; h < 8; ++h) pm += esc[i][h];
        arow[slist[i]] = pm * 0.125f;
    }

    const int c0 = tid * 2;
    const int h0 = c0 >> 6;
    float acc0 = 0.f, acc1 = 0.f;
    for (int i = 0; i < cnt; ++i) {
        const int s = slist[i];
        const float p = esc[i][h0];
        const ushort2v vv = *(const ushort2v*)(v_ws + ((size_t)b * NSEQ + s) * CMODEL + c0);
        acc0 += p * bf2f(vv[0]); acc1 += p * bf2f(vv[1]);
    }
    unsigned short* crow = ctx + ((size_t)t * BATCH + b) * CMODEL;
    ushort2v cv; cv[0] = f2bf(acc0); cv[1] = f2bf(acc1);
    *(ushort2v*)(crow + c0) = cv;
}

// ---------------------------------------------------------------------------
extern "C" void kernel_launch(void* const* d_in, const int* in_sizes, int n_in,
                              void* d_out, int out_size, void* d_ws, size_t ws_size,
                              hipStream_t stream) {
    (void)in_sizes; (void)n_in; (void)out_size; (void)ws_size;

    const float* query = (const float*)d_in[0];
    const float* key_t = (const float*)d_in[1];
    const float* value = (const float*)d_in[2];
    const float* srcp  = (const float*)d_in[3];
    const float* tgtp  = (const float*)d_in[4];
    const float* Wq    = (const float*)d_in[5];
    const float* Wk    = (const float*)d_in[6];
    const float* Wv    = (const float*)d_in[7];
    const float* bq    = (const float*)d_in[8];
    const float* bk    = (const float*)d_in[9];
    const float* bv    = (const float*)d_in[10];
    const float* Wo    = (const float*)d_in[11];
    const float* bo    = (const float*)d_in[12];

    float* out      = (float*)d_out;                          // (N,B,C)
    float* attn_out = out + (size_t)NSEQ * BATCH * CMODEL;    // (B,N,N)

    const size_t NBC = (size_t)BATCH * NSEQ * CMODEL;         // 4,194,304
    const size_t WSZ = (size_t)CMODEL * CMODEL;               // 262,144
    unsigned short* q_ws  = (unsigned short*)d_ws;
    unsigned short* k_ws  = q_ws + NBC;
    unsigned short* v_ws  = k_ws + NBC;
    unsigned short* ctxbf = v_ws + NBC;
    unsigned short* qbf   = ctxbf + NBC;                      // converted inputs
    unsigned short* kbf   = qbf + NBC;
    unsigned short* vbf   = kbf + NBC;
    unsigned short* wqbf  = vbf + NBC;
    unsigned short* wkbf  = wqbf + WSZ;
    unsigned short* wvbf  = wkbf + WSZ;
    unsigned short* wobf  = wvbf + WSZ;
    int*   row_cnt  = (int*)(wobf + WSZ);                     // 8192 ints
    float* vm       = (float*)(row_cnt + BATCH * NSEQ);       // 4096 floats
    float* vm_raw   = vm + BATCH * CMODEL;                    // 4096 floats
    float* tgt_soa  = vm_raw + BATCH * CMODEL;                // 24576 floats
    float* src_soa  = tgt_soa + (size_t)BATCH * 3 * NSEQ;     // 24576 floats
    int*   row_list = (int*)(src_soa + (size_t)BATCH * 3 * NSEQ);

    prepA<<<624, 256, 0, stream>>>(Wq, Wk, Wv, Wo, value, tgtp, srcp,
                                   wqbf, wkbf, wvbf, wobf,
                                   (unsigned int*)row_cnt, vm_raw,
                                   tgt_soa, src_soa);

    megaB<<<8200, 256, 0, stream>>>(query, key_t, value, qbf, kbf, vbf,
                                    src_soa, tgt_soa, row_cnt, row_list,
                                    wvbf, bv, vm_raw, vm);

    gemm_proj<<<768, 256, 0, stream>>>(qbf, kbf, vbf,
                                       wqbf, wkbf, wvbf,
                                       bq, bk, bv,
                                       q_ws, k_ws, v_ws);

    sparse_attn<<<dim3(NSEQ, BATCH), 256, 0, stream>>>(q_ws, k_ws, v_ws, row_cnt,
                                                       row_list, vm, ctxbf, attn_out);

    gemm_out<<<512, 256, 0, stream>>>(ctxbf, wobf, bo, out);
}

// Round 12
// 94.368 us; speedup vs baseline: 1.0992x; 1.0992x over previous
//
#include <hip/hip_runtime.h>
#include <cstdint>
#include <cstddef>

#define NSEQ 1024
#define BATCH 8
#define CMODEL 512
#define NHEAD 8
#define HDIM 64
#define CAP 64
#define FLTMAX 3.402823466e+38f

typedef short bf16x8 __attribute__((ext_vector_type(8)));
typedef float f32x4 __attribute__((ext_vector_type(4)));
typedef unsigned short ushort8v __attribute__((ext_vector_type(8)));
typedef unsigned short ushort2v __attribute__((ext_vector_type(2)));
typedef unsigned long long u64;

__device__ inline unsigned short f2bf(float f) {
    unsigned int u = __builtin_bit_cast(unsigned int, f);
    u += 0x7fffu + ((u >> 16) & 1u);
    return (unsigned short)(u >> 16);
}
__device__ inline float bf2f(unsigned short u) {
    return __builtin_bit_cast(float, (unsigned int)u << 16);
}

#define GLDS16(gsrc, ldst) \
    __builtin_amdgcn_global_load_lds((const __attribute__((address_space(1))) void*)(gsrc), \
                                     (__attribute__((address_space(3))) void*)(ldst), 16, 0, 0)

// ---------------------------------------------------------------------------
// prepA: blocks 0..511 weight fp32->bf16; 512..543 zero row_cnt;
// 544..607 column-sum of value (vm_raw); 608..623 SoA transpose of positions.
// ---------------------------------------------------------------------------
__global__ __launch_bounds__(256) void prepA(const float* __restrict__ w0,
                                             const float* __restrict__ w1,
                                             const float* __restrict__ w2,
                                             const float* __restrict__ w3,
                                             const float* __restrict__ value,
                                             const float* __restrict__ tgtp,
                                             const float* __restrict__ srcp,
                                             unsigned short* __restrict__ o0,
                                             unsigned short* __restrict__ o1,
                                             unsigned short* __restrict__ o2,
                                             unsigned short* __restrict__ o3,
                                             unsigned int* __restrict__ zp,
                                             float* __restrict__ vm_raw,
                                             float* __restrict__ tgt_soa,
                                             float* __restrict__ src_soa) {
    const int bid = blockIdx.x;
    const int tid = threadIdx.x;
    if (bid < 512) {
        const int idx = bid * 256 + tid;
        const int seg = idx >> 15;
        const int c   = idx & 32767;
        const float* src = seg == 0 ? w0 : seg == 1 ? w1 : seg == 2 ? w2 : w3;
        unsigned short* dst = seg == 0 ? o0 : seg == 1 ? o1 : seg == 2 ? o2 : o3;
        const float4 v0 = *(const float4*)(src + (size_t)c * 8);
        const float4 v1 = *(const float4*)(src + (size_t)c * 8 + 4);
        ushort8v u;
        u[0] = f2bf(v0.x); u[1] = f2bf(v0.y); u[2] = f2bf(v0.z); u[3] = f2bf(v0.w);
        u[4] = f2bf(v1.x); u[5] = f2bf(v1.y); u[6] = f2bf(v1.z); u[7] = f2bf(v1.w);
        *(ushort8v*)(dst + (size_t)c * 8) = u;
        return;
    }
    if (bid < 544) {
        zp[(bid - 512) * 256 + tid] = 0u;
        return;
    }
    if (bid < 608) {
        const int cb = bid - 544;
        const int b = cb >> 3, cg = cb & 7;
        const int ts = tid >> 6, c = cg * 64 + (tid & 63);
        float s = 0.f;
        for (int i = 0; i < 256; ++i) {
            const int t = ts * 256 + i;
            s += value[((size_t)t * BATCH + b) * CMODEL + c];
        }
        __shared__ float sh[4][64];
        sh[ts][tid & 63] = s;
        __syncthreads();
        if (ts == 0)
            vm_raw[b * CMODEL + c] = sh[0][tid & 63] + sh[1][tid & 63] +
                                     sh[2][tid & 63] + sh[3][tid & 63];
        return;
    }
    const int tb = bid - 608;
    const int which = tb >> 3, b = tb & 7;
    const float* src = which == 0 ? tgtp : srcp;
    float* dst = which == 0 ? tgt_soa : src_soa;
    for (int t = tid; t < NSEQ; t += 256) {
        const float* p = src + ((size_t)t * BATCH + b) * 3;
        dst[(b * 3 + 0) * NSEQ + t] = p[0];
        dst[(b * 3 + 1) * NSEQ + t] = p[1];
        dst[(b * 3 + 2) * NSEQ + t] = p[2];
    }
}

// u64 compare-exchange: a <- min, b <- max
#define CX64(a, b) { const bool _c = (a) < (b); const u64 _mn = _c ? (a) : (b); \
                     const u64 _mx = _c ? (b) : (a); (a) = _mn; (b) = _mx; }

// ---------------------------------------------------------------------------
// megaB: complementary fusion.
// blocks 0..31     : vm GEMV, coalesced (wave-per-32-outputs, lanes sweep k)
// blocks 32..2079  : wave-parallel top-5 (sorted-insert + butterfly merge)
// blocks 2080..8223: q/k/v fp32->bf16 convert (pure HBM streaming)
// ---------------------------------------------------------------------------
__global__ __launch_bounds__(256) void megaB(const float* __restrict__ a0,
                                             const float* __restrict__ a1,
                                             const float* __restrict__ a2,
                                             unsigned short* __restrict__ oa0,
                                             unsigned short* __restrict__ oa1,
                                             unsigned short* __restrict__ oa2,
                                             const float* __restrict__ src_soa,
                                             const float* __restrict__ tgt_soa,
                                             int* __restrict__ row_cnt,
                                             int* __restrict__ row_list,
                                             const unsigned short* __restrict__ Wv,
                                             const float* __restrict__ bv,
                                             const float* __restrict__ vm_raw,
                                             float* __restrict__ vm) {
    const int p = blockIdx.x;
    const int tid = threadIdx.x;

    if (p < 32) {
        // coalesced GEMV: vm[b][c] = (vm_raw[b,:]/1024) @ Wv^T + bv
        const int bsel = p >> 2, quad = p & 3;
        const int w = tid >> 6, lane = tid & 63;
        const float* vr = vm_raw + bsel * CMODEL;
        const float4 va = *(const float4*)(vr + lane * 8);
        const float4 vb = *(const float4*)(vr + lane * 8 + 4);
        float vp[8] = {va.x, va.y, va.z, va.w, vb.x, vb.y, vb.z, vb.w};
        for (int i = 0; i < 32; ++i) {
            const int c = quad * 128 + w * 32 + i;
            const ushort8v wv = *(const ushort8v*)(Wv + (size_t)c * CMODEL + lane * 8);
            float s = 0.f;
            #pragma unroll
            for (int j = 0; j < 8; ++j) s += vp[j] * bf2f(wv[j]);
            #pragma unroll
            for (int off = 1; off < 64; off <<= 1) s += __shfl_xor(s, off);
            if (lane == 0) vm[bsel * CMODEL + c] = s * (1.f / (float)NSEQ) + bv[c];
        }
        return;
    }

    if (p >= 2080) {
        const unsigned int idx = (unsigned int)(p - 2080) * 256u + tid;   // < 1572864
        const unsigned int seg = idx >> 19;
        const unsigned int c   = idx & 524287u;
        const float* src = seg == 0 ? a0 : seg == 1 ? a1 : a2;
        unsigned short* dst = seg == 0 ? oa0 : seg == 1 ? oa1 : oa2;
        const float4 v0 = *(const float4*)(src + (size_t)c * 8);
        const float4 v1 = *(const float4*)(src + (size_t)c * 8 + 4);
        ushort8v u;
        u[0] = f2bf(v0.x); u[1] = f2bf(v0.y); u[2] = f2bf(v0.z); u[3] = f2bf(v0.w);
        u[4] = f2bf(v1.x); u[5] = f2bf(v1.y); u[6] = f2bf(v1.z); u[7] = f2bf(v1.w);
        *(ushort8v*)(dst + (size_t)c * 8) = u;
        return;
    }

    // ---- top-5 via per-lane sorted insert + 6-step butterfly merge ----
    const int w = tid >> 6, lane = tid & 63;
    const int wg = (p - 32) * 4 + w;            // 0..8191
    const int s = wg & 1023, b = wg >> 10;

    const float* tx = tgt_soa + (b * 3 + 0) * NSEQ;
    const float* ty = tgt_soa + (b * 3 + 1) * NSEQ;
    const float* tz = tgt_soa + (b * 3 + 2) * NSEQ;
    const float sx = src_soa[(b * 3 + 0) * NSEQ + s];
    const float sy = src_soa[(b * 3 + 1) * NSEQ + s];
    const float sz = src_soa[(b * 3 + 2) * NSEQ + s];

    // sorted ascending (v0 smallest); key = (float bits of dist)<<32 | t
    u64 v0 = ~0ull, v1 = ~0ull, v2 = ~0ull, v3 = ~0ull, v4 = ~0ull;

    #pragma unroll
    for (int i = 0; i < 16; ++i) {
        const int t = i * 64 + lane;
        const float dx = tx[t] - sx;
        const float dy = ty[t] - sy;
        const float dz = tz[t] - sz;
        const float d = dx * dx + dy * dy + dz * dz;
        u64 x = ((u64)__builtin_bit_cast(unsigned int, d) << 32) | (unsigned int)t;
        if (x < v4) {                       // belongs in the top-5 so far
            CX64(v0, x);                    // bubble-through keeps list sorted
            CX64(v1, x);
            CX64(v2, x);
            CX64(v3, x);
            CX64(v4, x);
        }
    }

    #pragma unroll
    for (int off = 1; off < 64; off <<= 1) {
        // partner's list, reverse-paired (bitonic split: a_i vs b_{4-i})
        const u64 p0 = __shfl_xor(v4, off);
        const u64 p1 = __shfl_xor(v3, off);
        const u64 p2 = __shfl_xor(v2, off);
        const u64 p3 = __shfl_xor(v1, off);
        const u64 p4 = __shfl_xor(v0, off);
        v0 = v0 < p0 ? v0 : p0;             // keep lower half = 5 smallest of union
        v1 = v1 < p1 ? v1 : p1;
        v2 = v2 < p2 ? v2 : p2;
        v3 = v3 < p3 ? v3 : p3;
        v4 = v4 < p4 ? v4 : p4;
        // re-sort 5 (Bose-Nelson 9-comparator network)
        CX64(v0, v1); CX64(v3, v4); CX64(v2, v4); CX64(v2, v3); CX64(v1, v4);
        CX64(v0, v3); CX64(v0, v2); CX64(v1, v3); CX64(v1, v2);
    }

    if (lane == 0) {
        const u64 win[5] = {v0, v1, v2, v3, v4};
        #pragma unroll
        for (int k = 0; k < 5; ++k) {
            const int tt = (int)(unsigned int)win[k];   // low 32 bits = t
            const int pos = atomicAdd(&row_cnt[b * NSEQ + tt], 1);
            if (pos < CAP) row_list[((size_t)b * NSEQ + tt) * CAP + pos] = s;
        }
    }
}

// ---------------------------------------------------------------------------
// gemm_proj: all-GLDS ring-3 counted-vmcnt body (bf16 A) + bijective XCD
// swizzle over a 1D grid of 768. (R11, unchanged.)
// ---------------------------------------------------------------------------
__global__ __launch_bounds__(256, 3) void gemm_proj(const unsigned short* __restrict__ Aq,
                                                    const unsigned short* __restrict__ Ak,
                                                    const unsigned short* __restrict__ Av,
                                                    const unsigned short* __restrict__ Wq,
                                                    const unsigned short* __restrict__ Wk,
                                                    const unsigned short* __restrict__ Wv,
                                                    const float* __restrict__ bq,
                                                    const float* __restrict__ bk,
                                                    const float* __restrict__ bv,
                                                    unsigned short* __restrict__ oq,
                                                    unsigned short* __restrict__ ok,
                                                    unsigned short* __restrict__ ov) {
    __shared__ __align__(16) unsigned short smem[3 * 8192];
    const int p = blockIdx.x;                       // 0..767
    const int logical = (p & 7) * 96 + (p >> 3);
    const int z = logical >> 8;
    const int r = logical & 255;
    const int m0 = (r >> 2) * 128, n0 = (r & 3) * 128;
    const unsigned short* Abf = z == 0 ? Aq : z == 1 ? Ak : Av;
    const unsigned short* Wbf = z == 0 ? Wq : z == 1 ? Wk : Wv;
    const float* bias = z == 0 ? bq : z == 1 ? bk : bv;
    unsigned short* outp = z == 0 ? oq : z == 1 ? ok : ov;
    const float scale = z == 0 ? 0.125f : 1.0f;

    const int tid = threadIdx.x;
    const int l = tid & 63, w = tid >> 6;
    const int wr = (w >> 1) * 64, wc = (w & 1) * 64;
    const int lr = l & 15, g = l >> 4;

    f32x4 acc[4][4] = {};

    const int rowX = tid >> 2;
    const int kg0  = (tid & 3) ^ ((rowX >> 1) & 3);
    const unsigned short* aS0 = Abf + (size_t)(m0 + rowX) * CMODEL + kg0 * 8;
    const unsigned short* aS1 = aS0 + (size_t)64 * CMODEL;
    const unsigned short* bS0 = Wbf + (size_t)(n0 + rowX) * CMODEL + kg0 * 8;
    const unsigned short* bS1 = bS0 + (size_t)64 * CMODEL;
    const int wb = w * 512;

    auto STAGE = [&](int k0, int buf) {
        unsigned short* bb = smem + buf * 8192;
        GLDS16(aS0 + k0, bb + wb);
        GLDS16(aS1 + k0, bb + 2048 + wb);
        GLDS16(bS0 + k0, bb + 4096 + wb);
        GLDS16(bS1 + k0, bb + 6144 + wb);
    };
    auto COMPUTE = [&](const unsigned short* base) {
        bf16x8 af[4], bg[4];
        #pragma unroll
        for (int i = 0; i < 4; ++i) {
            const int ra = wr + i * 16 + lr;
            af[i] = *(const bf16x8*)(base + ra * 32 + ((g ^ ((ra >> 1) & 3)) << 3));
        }
        #pragma unroll
        for (int j = 0; j < 4; ++j) {
            const int rb = wc + j * 16 + lr;
            bg[j] = *(const bf16x8*)(base + 4096 + rb * 32 + ((g ^ ((rb >> 1) & 3)) << 3));
        }
        #pragma unroll
        for (int i = 0; i < 4; ++i)
            #pragma unroll
            for (int j = 0; j < 4; ++j)
                acc[i][j] = __builtin_amdgcn_mfma_f32_16x16x32_bf16(af[i], bg[j], acc[i][j], 0, 0, 0);
    };

    STAGE(0, 0);
    STAGE(32, 1);

    int cur = 0;
    for (int t = 0; t < 15; ++t) {
        asm volatile("s_waitcnt vmcnt(4)" ::: "memory");
        __builtin_amdgcn_s_barrier();
        if (t < 14) {
            int nb = cur + 2; if (nb >= 3) nb -= 3;
            STAGE((t + 2) * 32, nb);
        }
        COMPUTE(smem + cur * 8192);
        ++cur; if (cur == 3) cur = 0;
    }
    asm volatile("s_waitcnt vmcnt(0)" ::: "memory");
    __builtin_amdgcn_s_barrier();
    COMPUTE(smem + cur * 8192);

    #pragma unroll
    for (int i = 0; i < 4; ++i) {
        #pragma unroll
        for (int j = 0; j < 4; ++j) {
            const int col = n0 + wc + j * 16 + lr;
            const float bcol = bias[col];
            #pragma unroll
            for (int rr = 0; rr < 4; ++rr) {
                const int row = m0 + wr + i * 16 + g * 4 + rr;
                const float val = (acc[i][j][rr] + bcol) * scale;
                const int t = row >> 3, bb = row & 7;
                outp[((size_t)(bb * NSEQ + t)) * CMODEL + col] = f2bf(val);
            }
        }
    }
}

// ---------------------------------------------------------------------------
// gemm_out: all-GLDS ring-3, tile 128x64, 512 blocks (2/CU), vmcnt(3).
// ---------------------------------------------------------------------------
__global__ __launch_bounds__(256, 3) void gemm_out(const unsigned short* __restrict__ Abf,
                                                   const unsigned short* __restrict__ Wbf,
                                                   const float* __restrict__ bias,
                                                   float* __restrict__ out) {
    __shared__ __align__(16) unsigned short smem[3 * 6144];
    const int p = blockIdx.x;                       // 0..511
    const int logical = (p & 7) * 64 + (p >> 3);
    const int m0 = (logical >> 3) * 128, n0 = (logical & 7) * 64;

    const int tid = threadIdx.x;
    const int l = tid & 63, w = tid >> 6;
    const int wr = (w >> 1) * 64, wc = (w & 1) * 32;
    const int lr = l & 15, g = l >> 4;

    f32x4 acc[4][2] = {};

    const int rowX = tid >> 2;
    const int kg0  = (tid & 3) ^ ((rowX >> 1) & 3);
    const unsigned short* aS0 = Abf + (size_t)(m0 + rowX) * CMODEL + kg0 * 8;
    const unsigned short* aS1 = aS0 + (size_t)64 * CMODEL;
    const unsigned short* bS0 = Wbf + (size_t)(n0 + rowX) * CMODEL + kg0 * 8;
    const int wb = w * 512;

    auto STAGE = [&](int k0, int buf) {
        unsigned short* bb = smem + buf * 6144;
        GLDS16(aS0 + k0, bb + wb);
        GLDS16(aS1 + k0, bb + 2048 + wb);
        GLDS16(bS0 + k0, bb + 4096 + wb);
    };
    auto COMPUTE = [&](const unsigned short* base) {
        bf16x8 af[4], bg[2];
        #pragma unroll
        for (int i = 0; i < 4; ++i) {
            const int ra = wr + i * 16 + lr;
            af[i] = *(const bf16x8*)(base + ra * 32 + ((g ^ ((ra >> 1) & 3)) << 3));
        }
        #pragma unroll
        for (int j = 0; j < 2; ++j) {
            const int rb = wc + j * 16 + lr;
            bg[j] = *(const bf16x8*)(base + 4096 + rb * 32 + ((g ^ ((rb >> 1) & 3)) << 3));
        }
        #pragma unroll
        for (int i = 0; i < 4; ++i)
            #pragma unroll
            for (int j = 0; j < 2; ++j)
                acc[i][j] = __builtin_amdgcn_mfma_f32_16x16x32_bf16(af[i], bg[j], acc[i][j], 0, 0, 0);
    };

    STAGE(0, 0);
    STAGE(32, 1);

    int cur = 0;
    for (int t = 0; t < 15; ++t) {
        asm volatile("s_waitcnt vmcnt(3)" ::: "memory");
        __builtin_amdgcn_s_barrier();
        if (t < 14) {
            int nb = cur + 2; if (nb >= 3) nb -= 3;
            STAGE((t + 2) * 32, nb);
        }
        COMPUTE(smem + cur * 6144);
        ++cur; if (cur == 3) cur = 0;
    }
    asm volatile("s_waitcnt vmcnt(0)" ::: "memory");
    __builtin_amdgcn_s_barrier();
    COMPUTE(smem + cur * 6144);

    #pragma unroll
    for (int i = 0; i < 4; ++i) {
        #pragma unroll
        for (int j = 0; j < 2; ++j) {
            const int col = n0 + wc + j * 16 + lr;
            const float bcol = bias[col];
            #pragma unroll
            for (int r = 0; r < 4; ++r) {
                const int row = m0 + wr + i * 16 + g * 4 + r;
                out[(size_t)row * CMODEL + col] = acc[i][j][r] + bcol;
            }
        }
    }
}

// ---------------------------------------------------------------------------
// sparse_attn: unchanged. One block per (t, b). bf16 q/k/v.
// ---------------------------------------------------------------------------
__global__ __launch_bounds__(256) void sparse_attn(const unsigned short* __restrict__ q_ws,
                                                   const unsigned short* __restrict__ k_ws,
                                                   const unsigned short* __restrict__ v_ws,
                                                   const int* __restrict__ row_cnt,
                                                   const int* __restrict__ row_list,
                                                   const float* __restrict__ vm,
                                                   unsigned short* __restrict__ ctx,
                                                   float* __restrict__ attn_out) {
    const int t = blockIdx.x;
    const int b = blockIdx.y;
    const int tid = threadIdx.x;

    int cnt = row_cnt[b * NSEQ + t];
    if (cnt > CAP) cnt = CAP;

    float* arow = attn_out + ((size_t)b * NSEQ + t) * NSEQ;

    if (cnt == 0) {
        const float u = 1.f / (float)NSEQ;
        const float4 uv = {u, u, u, u};
        ((float4*)arow)[tid] = uv;
        for (int c = tid; c < CMODEL; c += 256)
            ctx[((size_t)t * BATCH + b) * CMODEL + c] = f2bf(vm[b * CMODEL + c]);
        return;
    }

    {
        const float4 zv = {0.f, 0.f, 0.f, 0.f};
        ((float4*)arow)[tid] = zv;
    }

    __shared__ float qs[CMODEL];
    __shared__ float esc[CAP][8];
    __shared__ float denom[8];
    __shared__ int   slist[CAP];

    if (tid < 8) denom[tid] = 0.f;
    if (tid < cnt) slist[tid] = row_list[((size_t)b * NSEQ + t) * CAP + tid];
    {
        const ushort2v qv = *(const ushort2v*)(q_ws + ((size_t)b * NSEQ + t) * CMODEL + tid * 2);
        qs[tid * 2] = bf2f(qv[0]); qs[tid * 2 + 1] = bf2f(qv[1]);
    }
    __syncthreads();

    const int wid = tid >> 6, lane = tid & 63;
    for (int i = wid; i < cnt; i += 4) {
        const int s = slist[i];
        const ushort8v kv = *(const ushort8v*)(k_ws + ((size_t)b * NSEQ + s) * CMODEL + lane * 8);
        const float* qrow = qs + lane * 8;
        float part = 0.f;
        #pragma unroll
        for (int j = 0; j < 8; ++j) part += qrow[j] * bf2f(kv[j]);
        part += __shfl_xor(part, 1);
        part += __shfl_xor(part, 2);
        part += __shfl_xor(part, 4);
        if ((lane & 7) == 0) {
            const int h = lane >> 3;
            const float e = __expf(part);
            esc[i][h] = e;
            atomicAdd(&denom[h], e);
        }
    }
    __syncthreads();

    for (int x = tid; x < cnt * 8; x += 256)
        esc[x >> 3][x & 7] /= denom[x & 7];
    __syncthreads();

    for (int i = tid; i < cnt; i += 256) {
        float pm = 0.f;
        #pragma unroll
        for (int h = 0; h < 8; ++h) pm += esc[i][h];
        arow[slist[i]] = pm * 0.125f;
    }

    const int c0 = tid * 2;
    const int h0 = c0 >> 6;
    float acc0 = 0.f, acc1 = 0.f;
    for (int i = 0; i < cnt; ++i) {
        const int s = slist[i];
        const float p = esc[i][h0];
        const ushort2v vv = *(const ushort2v*)(v_ws + ((size_t)b * NSEQ + s) * CMODEL + c0);
        acc0 += p * bf2f(vv[0]); acc1 += p * bf2f(vv[1]);
    }
    unsigned short* crow = ctx + ((size_t)t * BATCH + b) * CMODEL;
    ushort2v cv; cv[0] = f2bf(acc0); cv[1] = f2bf(acc1);
    *(ushort2v*)(crow + c0) = cv;
}

// ---------------------------------------------------------------------------
extern "C" void kernel_launch(void* const* d_in, const int* in_sizes, int n_in,
                              void* d_out, int out_size, void* d_ws, size_t ws_size,
                              hipStream_t stream) {
    (void)in_sizes; (void)n_in; (void)out_size; (void)ws_size;

    const float* query = (const float*)d_in[0];
    const float* key_t = (const float*)d_in[1];
    const float* value = (const float*)d_in[2];
    const float* srcp  = (const float*)d_in[3];
    const float* tgtp  = (const float*)d_in[4];
    const float* Wq    = (const float*)d_in[5];
    const float* Wk    = (const float*)d_in[6];
    const float* Wv    = (const float*)d_in[7];
    const float* bq    = (const float*)d_in[8];
    const float* bk    = (const float*)d_in[9];
    const float* bv    = (const float*)d_in[10];
    const float* Wo    = (const float*)d_in[11];
    const float* bo    = (const float*)d_in[12];

    float* out      = (float*)d_out;                          // (N,B,C)
    float* attn_out = out + (size_t)NSEQ * BATCH * CMODEL;    // (B,N,N)

    const size_t NBC = (size_t)BATCH * NSEQ * CMODEL;         // 4,194,304
    const size_t WSZ = (size_t)CMODEL * CMODEL;               // 262,144
    unsigned short* q_ws  = (unsigned short*)d_ws;
    unsigned short* k_ws  = q_ws + NBC;
    unsigned short* v_ws  = k_ws + NBC;
    unsigned short* ctxbf = v_ws + NBC;
    unsigned short* qbf   = ctxbf + NBC;                      // converted inputs
    unsigned short* kbf   = qbf + NBC;
    unsigned short* vbf   = kbf + NBC;
    unsigned short* wqbf  = vbf + NBC;
    unsigned short* wkbf  = wqbf + WSZ;
    unsigned short* wvbf  = wkbf + WSZ;
    unsigned short* wobf  = wvbf + WSZ;
    int*   row_cnt  = (int*)(wobf + WSZ);                     // 8192 ints
    float* vm       = (float*)(row_cnt + BATCH * NSEQ);       // 4096 floats
    float* vm_raw   = vm + BATCH * CMODEL;                    // 4096 floats
    float* tgt_soa  = vm_raw + BATCH * CMODEL;                // 24576 floats
    float* src_soa  = tgt_soa + (size_t)BATCH * 3 * NSEQ;     // 24576 floats
    int*   row_list = (int*)(src_soa + (size_t)BATCH * 3 * NSEQ);

    prepA<<<624, 256, 0, stream>>>(Wq, Wk, Wv, Wo, value, tgtp, srcp,
                                   wqbf, wkbf, wvbf, wobf,
                                   (unsigned int*)row_cnt, vm_raw,
                                   tgt_soa, src_soa);

    megaB<<<8224, 256, 0, stream>>>(query, key_t, value, qbf, kbf, vbf,
                                    src_soa, tgt_soa, row_cnt, row_list,
                                    wvbf, bv, vm_raw, vm);

    gemm_proj<<<768, 256, 0, stream>>>(qbf, kbf, vbf,
                                       wqbf, wkbf, wvbf,
                                       bq, bk, bv,
                                       q_ws, k_ws, v_ws);

    sparse_attn<<<dim3(NSEQ, BATCH), 256, 0, stream>>>(q_ws, k_ws, v_ws, row_cnt,
                                                       row_list, vm, ctxbf, attn_out);

    gemm_out<<<512, 256, 0, stream>>>(ctxbf, wobf, bo, out);
}